// Round 1
// baseline (95.249 us; speedup 1.0000x reference)
//
#include <hip/hip_runtime.h>

// Problem constants (from reference): B=4096, V=32000, L=50.
#define V_ 32000
#define L_ 50
#define BLOCK_ 256

// One 256-thread block per batch row.
//  - all 4 waves stream the row with float4 loads, accumulating sum(exp)
//  - wave 0 additionally gathers target score + 50 tail scores up-front
//    (latency hidden under the stream), then computes the Plackett-Luce
//    tail term wave-parallel: suffix-sum of exp_s via __shfl_down scan,
//    per-lane log terms, wave reduction.
__global__ __launch_bounds__(BLOCK_) void longtail_loss_kernel(
    const float* __restrict__ output,       // [B, V]
    const int*   __restrict__ target,       // [B]
    const int*   __restrict__ longtail,     // [B, L]
    const float* __restrict__ loss_weight,  // [V]
    float* __restrict__ out)                // [B]
{
    const int b    = blockIdx.x;
    const int tid  = threadIdx.x;
    const int lane = tid & 63;
    const int wave = tid >> 6;
    const float* __restrict__ row = output + (size_t)b * V_;

    // ---- wave 0: issue all gathers early (overlap with streaming) ----
    int   tgt = 0;
    float ts = 0.f, w = 0.f, s = 0.f;
    bool  valid = false;
    if (wave == 0) {
        tgt = target[b];
        ts  = row[tgt];           // broadcast gather (same addr all lanes)
        w   = loss_weight[tgt];
        if (lane < L_) {
            int lt  = longtail[b * L_ + lane];
            int idx = lt < 0 ? 0 : (lt > V_ - 1 ? V_ - 1 : lt);
            s     = row[idx];
            valid = lt > 0;
        }
    }

    // ---- all threads: streaming sum of exp over the row (float4) ----
    const float4* __restrict__ row4 = reinterpret_cast<const float4*>(row);
    float psum = 0.f;
    for (int i = tid; i < V_ / 4; i += BLOCK_) {
        float4 v = row4[i];
        psum += __expf(v.x) + __expf(v.y) + __expf(v.z) + __expf(v.w);
    }
    #pragma unroll
    for (int off = 32; off; off >>= 1) psum += __shfl_down(psum, off, 64);

    __shared__ float wsum[BLOCK_ / 64];
    if (lane == 0) wsum[wave] = psum;
    __syncthreads();

    if (wave != 0) return;

    const float sum_exp = wsum[0] + wsum[1] + wsum[2] + wsum[3];

    // exp of tail scores (0 for padding / lanes >= L)
    float e = valid ? __expf(s) : 0.f;

    // total tail mass
    float esum = e;
    #pragma unroll
    for (int off = 32; off; off >>= 1) esum += __shfl_down(esum, off, 64);
    esum = __shfl(esum, 0, 64);

    const float other = sum_exp - __expf(ts) - esum;

    // suffix sum: rc[lane] = sum_{j >= lane} e[j]  (6-step shfl scan)
    float rc = e;
    #pragma unroll
    for (int off = 1; off < 64; off <<= 1) {
        float t = __shfl_down(rc, off, 64);
        rc += (lane + off < 64) ? t : 0.f;
    }

    // per-lane PL term, then wave-reduce
    float term = valid ? (s - __logf(rc + other)) : 0.f;
    #pragma unroll
    for (int off = 32; off; off >>= 1) term += __shfl_down(term, off, 64);

    if (lane == 0) {
        const float log_pl = ts - __logf(sum_exp);
        out[b] = -(log_pl + term) + w;
    }
}

extern "C" void kernel_launch(void* const* d_in, const int* in_sizes, int n_in,
                              void* d_out, int out_size, void* d_ws, size_t ws_size,
                              hipStream_t stream) {
    const float* output      = (const float*)d_in[0];
    const int*   target      = (const int*)d_in[1];
    const int*   longtail    = (const int*)d_in[2];
    const float* loss_weight = (const float*)d_in[3];
    float*       out         = (float*)d_out;

    const int B = in_sizes[1];  // 4096
    longtail_loss_kernel<<<B, BLOCK_, 0, stream>>>(output, target, longtail,
                                                   loss_weight, out);
}

// Round 3
// 82.897 us; speedup vs baseline: 1.1490x; 1.1490x over previous
//
#include <hip/hip_runtime.h>

// Problem constants (from reference): B=4096, V=32000, L=50.
#define V_ 32000
#define L_ 50
#define BLOCK_ 256

// clang-native vector type (HIP's float4 is a class; the nontemporal
// builtin needs a real vector type).
typedef float fvec4 __attribute__((ext_vector_type(4)));

__device__ __forceinline__ float exp4(const fvec4 v) {
    return (__expf(v.x) + __expf(v.y)) + (__expf(v.z) + __expf(v.w));
}

// One 256-thread block per batch row.
//  - all 4 waves stream the row with nontemporal float4 loads (x4 unrolled,
//    4 independent accumulators -> 4 loads in flight per wave)
//  - wave 0 gathers target score + 50 tail scores up-front (latency hidden
//    under the stream), then computes the Plackett-Luce tail term
//    wave-parallel: suffix-sum via __shfl_down scan, per-lane logs, reduce.
__global__ __launch_bounds__(BLOCK_) void longtail_loss_kernel(
    const float* __restrict__ output,       // [B, V]
    const int*   __restrict__ target,       // [B]
    const int*   __restrict__ longtail,     // [B, L]
    const float* __restrict__ loss_weight,  // [V]
    float* __restrict__ out)                // [B]
{
    const int b    = blockIdx.x;
    const int tid  = threadIdx.x;
    const int lane = tid & 63;
    const int wave = tid >> 6;
    const float* __restrict__ row = output + (size_t)b * V_;

    // ---- wave 0: issue all gathers early (overlap with streaming) ----
    int   tgt = 0;
    float ts = 0.f, w = 0.f, s = 0.f;
    bool  valid = false;
    if (wave == 0) {
        tgt = target[b];
        ts  = row[tgt];           // broadcast gather (same addr all lanes)
        w   = loss_weight[tgt];
        if (lane < L_) {
            int lt  = longtail[b * L_ + lane];
            int idx = lt < 0 ? 0 : (lt > V_ - 1 ? V_ - 1 : lt);
            s     = row[idx];
            valid = lt > 0;
        }
    }

    // ---- all threads: streaming sum of exp over the row ----
    const fvec4* __restrict__ row4 = reinterpret_cast<const fvec4*>(row);
    const int n4 = V_ / 4;  // 8000
    float a0 = 0.f, a1 = 0.f, a2 = 0.f, a3 = 0.f;
    int i = tid;
    for (; i + 3 * BLOCK_ < n4; i += 4 * BLOCK_) {
        fvec4 v0 = __builtin_nontemporal_load(&row4[i]);
        fvec4 v1 = __builtin_nontemporal_load(&row4[i + BLOCK_]);
        fvec4 v2 = __builtin_nontemporal_load(&row4[i + 2 * BLOCK_]);
        fvec4 v3 = __builtin_nontemporal_load(&row4[i + 3 * BLOCK_]);
        a0 += exp4(v0);
        a1 += exp4(v1);
        a2 += exp4(v2);
        a3 += exp4(v3);
    }
    for (; i < n4; i += BLOCK_) {
        fvec4 v = __builtin_nontemporal_load(&row4[i]);
        a0 += exp4(v);
    }
    float psum = (a0 + a1) + (a2 + a3);

    #pragma unroll
    for (int off = 32; off; off >>= 1) psum += __shfl_down(psum, off, 64);

    __shared__ float wsum[BLOCK_ / 64];
    if (lane == 0) wsum[wave] = psum;
    __syncthreads();

    if (wave != 0) return;

    const float sum_exp = wsum[0] + wsum[1] + wsum[2] + wsum[3];

    // exp of tail scores (0 for padding / lanes >= L)
    float e = valid ? __expf(s) : 0.f;

    // total tail mass
    float esum = e;
    #pragma unroll
    for (int off = 32; off; off >>= 1) esum += __shfl_down(esum, off, 64);
    esum = __shfl(esum, 0, 64);

    const float other = sum_exp - __expf(ts) - esum;

    // suffix sum: rc[lane] = sum_{j >= lane} e[j]  (6-step shfl scan)
    float rc = e;
    #pragma unroll
    for (int off = 1; off < 64; off <<= 1) {
        float t = __shfl_down(rc, off, 64);
        rc += (lane + off < 64) ? t : 0.f;
    }

    // per-lane PL term, then wave-reduce
    float term = valid ? (s - __logf(rc + other)) : 0.f;
    #pragma unroll
    for (int off = 32; off; off >>= 1) term += __shfl_down(term, off, 64);

    if (lane == 0) {
        const float log_pl = ts - __logf(sum_exp);
        out[b] = -(log_pl + term) + w;
    }
}

extern "C" void kernel_launch(void* const* d_in, const int* in_sizes, int n_in,
                              void* d_out, int out_size, void* d_ws, size_t ws_size,
                              hipStream_t stream) {
    const float* output      = (const float*)d_in[0];
    const int*   target      = (const int*)d_in[1];
    const int*   longtail    = (const int*)d_in[2];
    const float* loss_weight = (const float*)d_in[3];
    float*       out         = (float*)d_out;

    const int B = in_sizes[1];  // 4096
    longtail_loss_kernel<<<B, BLOCK_, 0, stream>>>(output, target, longtail,
                                                   loss_weight, out);
}